// Round 3
// baseline (101.076 us; speedup 1.0000x reference)
//
#include <hip/hip_runtime.h>
#include <stdint.h>

// MulticlassDice — N=8 samples, C=8 classes, 512x512 px, int32 labels 0..7.
// Whole computation = 192 histogram counters (count_in, count_tg, inter per
// (n,c)) + tiny epilogue. 16 MiB stream -> ~2.7 us HBM floor.
//
// R3: SINGLE kernel node. 512 blocks count into private partial slots; the
// last block to finish (device-scope ticket) reduces partials and writes the
// 9 outputs. Ticket init relies on the documented 0xAA ws re-poison
// (0xAAAAAAAA), hedged with a zero-init fallback for the correctness call.

#define NCLS    8
#define NSAMP   8
#define PIX     (512 * 512)
#define BLKS    64            // blocks per sample; total grid = 8*64 = 512
#define SMOOTHF 1e-5f

typedef unsigned long long u64;
typedef unsigned int u32;

// ws layout:
//   u32 partial[NSAMP*BLKS][24]   (12288 u32)  counter i = set*8+c,
//       set 0 = count_in, 1 = count_tg, 2 = inter
//   u32 ticket                    (at index 12288)
#define TICKET_IDX (NSAMP * BLKS * 24)
#define POISON_U32 0xAAAAAAAAu

__global__ __launch_bounds__(256) void dice_fused(const int* __restrict__ in,
                                                  const int* __restrict__ tg,
                                                  u32* __restrict__ ws,
                                                  const float* __restrict__ w,
                                                  float* __restrict__ out) {
    const int n = blockIdx.y;
    const int t = threadIdx.x;
    const int4* in4 = (const int4*)(in + (size_t)n * PIX);
    const int4* tg4 = (const int4*)(tg + (size_t)n * PIX);
    const int base = blockIdx.x * 1024;  // int4 units; 64 blk * 1024 * 4 = 262144 px

    // ---- per-thread SWAR histogram: 16 px/thread, 8-bit field per class ----
    u64 pin = 0, ptg = 0, pix = 0;
#pragma unroll
    for (int i = 0; i < 4; ++i) {
        int4 a = in4[base + i * 256 + t];
        int4 b = tg4[base + i * 256 + t];
        u64 ax = 1ull << (a.x * 8), ay = 1ull << (a.y * 8);
        u64 az = 1ull << (a.z * 8), aw = 1ull << (a.w * 8);
        pin += ax + ay + az + aw;
        ptg += (1ull << (b.x * 8)) + (1ull << (b.y * 8)) +
               (1ull << (b.z * 8)) + (1ull << (b.w * 8));
        if (a.x == b.x) pix += ax;
        if (a.y == b.y) pix += ay;
        if (a.z == b.z) pix += az;
        if (a.w == b.w) pix += aw;
    }

    // Butterfly rounds 1-3 (offsets 1,2,4) on packed 8-bit fields (max 128 <= 255).
#pragma unroll
    for (int off = 1; off <= 4; off <<= 1) {
        pin += (u64)__shfl_xor((unsigned long long)pin, off, 64);
        ptg += (u64)__shfl_xor((unsigned long long)ptg, off, 64);
        pix += (u64)__shfl_xor((unsigned long long)pix, off, 64);
    }

    // Split 8-bit -> 16-bit fields, rounds 4-6 (max 1024 <= 65535).
    const u64 M = 0x00FF00FF00FF00FFull;
    u64 v[6];
    v[0] = pin & M;        // count_in, classes 0,2,4,6
    v[1] = (pin >> 8) & M; // count_in, classes 1,3,5,7
    v[2] = ptg & M;
    v[3] = (ptg >> 8) & M;
    v[4] = pix & M;
    v[5] = (pix >> 8) & M;
#pragma unroll
    for (int off = 8; off <= 32; off <<= 1) {
#pragma unroll
        for (int j = 0; j < 6; ++j)
            v[j] += (u64)__shfl_xor((unsigned long long)v[j], off, 64);
    }

    // ---- combine 4 waves via LDS, write block partial ----
    __shared__ u32 sm[4 * 24];
    const int wave = t >> 6;
    const int lane = t & 63;
    if (lane < 24) {
        const int set = lane >> 3;
        const int c   = lane & 7;
        u64 pk = v[set * 2 + (c & 1)];
        sm[wave * 24 + lane] = (u32)((pk >> (16 * (c >> 1))) & 0xFFFFull);
    }
    __syncthreads();
    if (t < 24) {
        u32 s = sm[t] + sm[24 + t] + sm[48 + t] + sm[72 + t];
        ws[((size_t)(n * BLKS + blockIdx.x)) * 24 + t] = s;
    }

    // ---- last-block-done ticket (canonical threadFenceReduction pattern) ----
    __threadfence();          // make this block's partial visible device-wide
    __syncthreads();          // order all threads' fences before the ticket
    __shared__ int amLast;
    if (t == 0) {
        u32 old = atomicAdd(&ws[TICKET_IDX], 1u);
        amLast = (old == POISON_U32 + 511u) |   // documented 0xAA re-poison
                 (old == 511u);                 // zero-init hedge
    }
    __syncthreads();
    if (!amLast) return;

    // ---- finalize: reduce 512 partials -> 192 counters -> dice ----
    __threadfence();          // acquire: see all other blocks' partials
    __shared__ u32 cnt[NSAMP * 24];
    if (t < 192) {
        const int sn = t / 24;
        const int i  = t - sn * 24;
        u32 s = 0;
#pragma unroll 8
        for (int b = 0; b < BLKS; ++b)
            s += ws[((size_t)(sn * BLKS + b)) * 24 + i];
        cnt[sn * 24 + i] = s;
    }
    __syncthreads();

    if (t < 64) {
        const int sn = t >> 3;
        const int c  = t & 7;
        float cin = (float)cnt[sn * 24 + 0 + c];
        float ctg = (float)cnt[sn * 24 + 8 + c];
        float itr = (float)cnt[sn * 24 + 16 + c];
        float dice = (2.0f * itr + SMOOTHF) / (cin + ctg + SMOOTHF);

        // Sum over samples (lanes differing in bits 3..5 share c).
        dice += __shfl_xor(dice, 8, 64);
        dice += __shfl_xor(dice, 16, 64);
        dice += __shfl_xor(dice, 32, 64);
        float mean_c = dice * 0.125f;

        if (t < 8) out[1 + t] = mean_c;

        float wsum = w[c] * mean_c;
        wsum += __shfl_xor(wsum, 1, 64);
        wsum += __shfl_xor(wsum, 2, 64);
        wsum += __shfl_xor(wsum, 4, 64);
        if (t == 0) out[0] = wsum;
    }
}

extern "C" void kernel_launch(void* const* d_in, const int* in_sizes, int n_in,
                              void* d_out, int out_size, void* d_ws, size_t ws_size,
                              hipStream_t stream) {
    const int*   in  = (const int*)d_in[0];
    const int*   tg  = (const int*)d_in[1];
    const float* w   = (const float*)d_in[2];
    float*       out = (float*)d_out;
    u32*         ws  = (u32*)d_ws;   // partials fully overwritten; ticket uses poison

    dice_fused<<<dim3(BLKS, NSAMP), 256, 0, stream>>>(in, tg, ws, w, out);
}

// Round 4
// 75.731 us; speedup vs baseline: 1.3347x; 1.3347x over previous
//
#include <hip/hip_runtime.h>
#include <stdint.h>

// MulticlassDice — N=8 samples, C=8 classes, 512x512 px, int32 labels 0..7.
// 192 histogram counters (count_in, count_tg, inter per (n,c)) + tiny epilogue.
// 16 MiB stream -> ~2.7 us HBM floor.
//
// R4: single kernel node, NO fences (R3's __threadfence emitted per-wave
// buffer_wbl2/buffer_inv L2 flushes on multi-XCD gfx950 -> +27 us).
// Blocks atomicAdd into 192 device counters (memory-side RMW, coherent by
// construction); explicit s_waitcnt + __syncthreads orders the adds before
// the ticket bump; last block reads counters with relaxed agent-scope atomic
// loads (sc-bit coherent, no buffer_inv). Counter/ticket base = ws poison
// (0xAAAAAAAA) or 0, disambiguated by exact checksum sum_c cnt_in[0][c].

#define NCLS    8
#define NSAMP   8
#define PIX     (512 * 512)
#define SPIX    262144        // pixels per sample
#define BLKS    64            // blocks per sample; grid = 8*64 = 512
#define NBLK    512
#define SMOOTHF 1e-5f

typedef unsigned long long u64;
typedef unsigned int u32;

// ws layout: u32 cnt[192] (i = n*24 + set*8 + c; set 0=count_in,1=count_tg,2=inter)
//            u32 ticket at index 192
#define TICKET_IDX 192
#define POISON_U32 0xAAAAAAAAu

__global__ __launch_bounds__(256) void dice_fused(const int* __restrict__ in,
                                                  const int* __restrict__ tg,
                                                  u32* __restrict__ ws,
                                                  const float* __restrict__ w,
                                                  float* __restrict__ out) {
    const int n = blockIdx.y;
    const int t = threadIdx.x;
    const int4* in4 = (const int4*)(in + (size_t)n * PIX);
    const int4* tg4 = (const int4*)(tg + (size_t)n * PIX);
    const int base = blockIdx.x * 1024;  // int4 units; 64 blk * 4096 px = 262144

    // ---- per-thread SWAR histogram: 16 px/thread, 8-bit field per class ----
    u64 pin = 0, ptg = 0, pix = 0;
#pragma unroll
    for (int i = 0; i < 4; ++i) {
        int4 a = in4[base + i * 256 + t];
        int4 b = tg4[base + i * 256 + t];
        u64 ax = 1ull << (a.x * 8), ay = 1ull << (a.y * 8);
        u64 az = 1ull << (a.z * 8), aw = 1ull << (a.w * 8);
        pin += ax + ay + az + aw;
        ptg += (1ull << (b.x * 8)) + (1ull << (b.y * 8)) +
               (1ull << (b.z * 8)) + (1ull << (b.w * 8));
        if (a.x == b.x) pix += ax;
        if (a.y == b.y) pix += ay;
        if (a.z == b.z) pix += az;
        if (a.w == b.w) pix += aw;
    }

    // Butterfly rounds 1-3 (offsets 1,2,4) on 8-bit fields (max 128 <= 255).
#pragma unroll
    for (int off = 1; off <= 4; off <<= 1) {
        pin += (u64)__shfl_xor((unsigned long long)pin, off, 64);
        ptg += (u64)__shfl_xor((unsigned long long)ptg, off, 64);
        pix += (u64)__shfl_xor((unsigned long long)pix, off, 64);
    }

    // Split 8-bit -> 16-bit fields, rounds 4-6 (max 1024 <= 65535).
    const u64 M = 0x00FF00FF00FF00FFull;
    u64 v[6];
    v[0] = pin & M;        // count_in, classes 0,2,4,6
    v[1] = (pin >> 8) & M; // count_in, classes 1,3,5,7
    v[2] = ptg & M;
    v[3] = (ptg >> 8) & M;
    v[4] = pix & M;
    v[5] = (pix >> 8) & M;
#pragma unroll
    for (int off = 8; off <= 32; off <<= 1) {
#pragma unroll
        for (int j = 0; j < 6; ++j)
            v[j] += (u64)__shfl_xor((unsigned long long)v[j], off, 64);
    }

    // ---- combine 4 waves via LDS; threads 0..23 hold block totals ----
    __shared__ u32 sm[4 * 24];
    const int wave = t >> 6;
    const int lane = t & 63;
    if (lane < 24) {
        const int set = lane >> 3;
        const int c   = lane & 7;
        u64 pk = v[set * 2 + (c & 1)];
        sm[wave * 24 + lane] = (u32)((pk >> (16 * (c >> 1))) & 0xFFFFull);
    }
    __syncthreads();
    if (t < 24) {
        u32 s = sm[t] + sm[24 + t] + sm[48 + t] + sm[72 + t];
        atomicAdd(&ws[n * 24 + t], s);   // device-scope RMW at coherent point
    }

    // Drain the atomics to the coherent point before the ticket bump.
    asm volatile("s_waitcnt vmcnt(0)" ::: "memory");
    __syncthreads();   // compiler also drains vmcnt before s_barrier

    __shared__ int amLast;
    if (t == 0) {
        u32 old = atomicAdd(&ws[TICKET_IDX], 1u);
        amLast = (old == (u32)(NBLK - 1)) |                 // zero-init path
                 (old == (u32)(POISON_U32 + NBLK - 1));     // 0xAA poison path
    }
    __syncthreads();
    if (!amLast) return;

    // ---- last block: coherent reads of 192 counters, subtract base, dice ----
    __shared__ u32 rawsh[192];
    if (t < 192)
        rawsh[t] = __hip_atomic_load(&ws[t], __ATOMIC_RELAXED,
                                     __HIP_MEMORY_SCOPE_AGENT);
    __syncthreads();

    if (t < 64) {
        // Runtime base detection: sum_c count_in[0][c] == SPIX + 8*B (mod 2^32).
        u32 s0 = 0;
#pragma unroll
        for (int c = 0; c < 8; ++c) s0 += rawsh[c];
        const u32 B = (s0 == (u32)SPIX) ? 0u : POISON_U32;

        const int sn = t >> 3;
        const int c  = t & 7;
        float cin = (float)(rawsh[sn * 24 + 0 + c]  - B);
        float ctg = (float)(rawsh[sn * 24 + 8 + c]  - B);
        float itr = (float)(rawsh[sn * 24 + 16 + c] - B);
        float dice = (2.0f * itr + SMOOTHF) / (cin + ctg + SMOOTHF);

        // Sum over samples (lanes differing in bits 3..5 share c).
        dice += __shfl_xor(dice, 8, 64);
        dice += __shfl_xor(dice, 16, 64);
        dice += __shfl_xor(dice, 32, 64);
        float mean_c = dice * 0.125f;

        if (t < 8) out[1 + t] = mean_c;

        float wsum = w[c] * mean_c;
        wsum += __shfl_xor(wsum, 1, 64);
        wsum += __shfl_xor(wsum, 2, 64);
        wsum += __shfl_xor(wsum, 4, 64);
        if (t == 0) out[0] = wsum;
    }
}

extern "C" void kernel_launch(void* const* d_in, const int* in_sizes, int n_in,
                              void* d_out, int out_size, void* d_ws, size_t ws_size,
                              hipStream_t stream) {
    const int*   in  = (const int*)d_in[0];
    const int*   tg  = (const int*)d_in[1];
    const float* w   = (const float*)d_in[2];
    float*       out = (float*)d_out;
    u32*         ws  = (u32*)d_ws;   // counters/ticket start at poison (or 0)

    dice_fused<<<dim3(BLKS, NSAMP), 256, 0, stream>>>(in, tg, ws, w, out);
}

// Round 5
// 74.002 us; speedup vs baseline: 1.3659x; 1.0234x over previous
//
#include <hip/hip_runtime.h>
#include <stdint.h>

// MulticlassDice — N=8 samples, C=8 classes, 512x512 px, int32 labels 0..7.
// Whole computation = 192 histogram counters (count_in, count_tg, inter per
// (n,c)) + tiny epilogue. 16 MiB stream -> ~2.7 us HBM floor.
//
// R5 = revert to R2 (best measured: 74.0 us). Two plain graph nodes, no
// atomics, no fences, no memset. Each block writes its own partial slot
// (unconditional overwrite of poisoned ws); dice_final reduces partials.
// Structural A/B history: 3 nodes w/ memset = 81.7; 2 nodes = 74.0;
// 1 node ticket+fence = 101.1 (agent-fence L2 flush); 1 node ticket+atomics
// = 75.7. Measured loop is dominated by the harness's 268 MB ws re-poison
// (~42 us @ 80% HBM peak) — outside kernel control.

#define NCLS    8
#define NSAMP   8
#define PIX     (512 * 512)
#define BLKS    64            // blocks per sample
#define SMOOTHF 1e-5f

typedef unsigned long long u64;
typedef unsigned int u32;

// ws layout: u32 partial[NSAMP*BLKS][24]
//   counter index i = set*8 + c,  set 0 = count_in, 1 = count_tg, 2 = inter.

// grid (BLKS, NSAMP) x 256 threads; 16 px/thread via 4 x int4 per array.
// Per-thread per-class count <= 16 (8-bit SWAR field safe).
// Butterfly rounds 1-3 on 8-bit fields (max 16*8=128 <= 255), then split to
// 16-bit fields for rounds 4-6 (max 16*64=1024 <= 65535).
__global__ __launch_bounds__(256) void dice_count(const int* __restrict__ in,
                                                  const int* __restrict__ tg,
                                                  u32* __restrict__ partial) {
    const int n = blockIdx.y;
    const int t = threadIdx.x;
    const int4* in4 = (const int4*)(in + (size_t)n * PIX);
    const int4* tg4 = (const int4*)(tg + (size_t)n * PIX);
    const int base = blockIdx.x * 1024;  // int4 units; 64 blk * 1024 * 4 = 262144 px

    u64 pin = 0, ptg = 0, pix = 0;  // 8-bit field per class
#pragma unroll
    for (int i = 0; i < 4; ++i) {
        int4 a = in4[base + i * 256 + t];
        int4 b = tg4[base + i * 256 + t];
        u64 ax = 1ull << (a.x * 8), ay = 1ull << (a.y * 8);
        u64 az = 1ull << (a.z * 8), aw = 1ull << (a.w * 8);
        pin += ax + ay + az + aw;
        ptg += (1ull << (b.x * 8)) + (1ull << (b.y * 8)) +
               (1ull << (b.z * 8)) + (1ull << (b.w * 8));
        if (a.x == b.x) pix += ax;
        if (a.y == b.y) pix += ay;
        if (a.z == b.z) pix += az;
        if (a.w == b.w) pix += aw;
    }

    // Rounds 1-3 (offsets 1,2,4) on packed 8-bit fields: 3 u64 shuffles/round.
#pragma unroll
    for (int off = 1; off <= 4; off <<= 1) {
        pin += (u64)__shfl_xor((unsigned long long)pin, off, 64);
        ptg += (u64)__shfl_xor((unsigned long long)ptg, off, 64);
        pix += (u64)__shfl_xor((unsigned long long)pix, off, 64);
    }

    // Split 8-bit -> 16-bit fields (even classes low set, odd classes high set).
    const u64 M = 0x00FF00FF00FF00FFull;
    u64 v[6];
    v[0] = pin & M;        // count_in, classes 0,2,4,6
    v[1] = (pin >> 8) & M; // count_in, classes 1,3,5,7
    v[2] = ptg & M;
    v[3] = (ptg >> 8) & M;
    v[4] = pix & M;
    v[5] = (pix >> 8) & M;

    // Rounds 4-6 (offsets 8,16,32).
#pragma unroll
    for (int off = 8; off <= 32; off <<= 1) {
#pragma unroll
        for (int j = 0; j < 6; ++j)
            v[j] += (u64)__shfl_xor((unsigned long long)v[j], off, 64);
    }

    // Every lane now holds the full wave sum. Combine 4 waves via LDS.
    __shared__ u32 sm[4 * 24];
    const int wave = t >> 6;
    const int lane = t & 63;
    if (lane < 24) {
        const int set = lane >> 3;
        const int c   = lane & 7;
        u64 pk = v[set * 2 + (c & 1)];
        sm[wave * 24 + lane] = (u32)((pk >> (16 * (c >> 1))) & 0xFFFFull);
    }
    __syncthreads();
    if (t < 24) {
        u32 s = sm[t] + sm[24 + t] + sm[48 + t] + sm[72 + t];
        partial[((size_t)(n * BLKS + blockIdx.x)) * 24 + t] = s;
    }
}

// One block, 192 threads (3 waves). Thread t -> (n = t/24, i = t%24):
// sum 64 block-partials, then wave 0 does the dice epilogue.
__global__ __launch_bounds__(192) void dice_final(const u32* __restrict__ partial,
                                                  const float* __restrict__ w,
                                                  float* __restrict__ out) {
    const int t = threadIdx.x;
    __shared__ u32 cnt[NSAMP * 24];

    const int n = t / 24;
    const int i = t - n * 24;
    u32 s = 0;
#pragma unroll 8
    for (int b = 0; b < BLKS; ++b)
        s += partial[((size_t)(n * BLKS + b)) * 24 + i];
    cnt[n * 24 + i] = s;
    __syncthreads();

    if (t < 64) {
        const int sn = t >> 3;
        const int c  = t & 7;
        float cin = (float)cnt[sn * 24 + 0 + c];
        float ctg = (float)cnt[sn * 24 + 8 + c];
        float itr = (float)cnt[sn * 24 + 16 + c];
        float dice = (2.0f * itr + SMOOTHF) / (cin + ctg + SMOOTHF);

        // Sum over samples (lanes differing in bits 3..5 share c).
        dice += __shfl_xor(dice, 8, 64);
        dice += __shfl_xor(dice, 16, 64);
        dice += __shfl_xor(dice, 32, 64);
        float mean_c = dice * 0.125f;

        if (t < 8) out[1 + t] = mean_c;

        float ws = w[c] * mean_c;
        ws += __shfl_xor(ws, 1, 64);
        ws += __shfl_xor(ws, 2, 64);
        ws += __shfl_xor(ws, 4, 64);
        if (t == 0) out[0] = ws;
    }
}

extern "C" void kernel_launch(void* const* d_in, const int* in_sizes, int n_in,
                              void* d_out, int out_size, void* d_ws, size_t ws_size,
                              hipStream_t stream) {
    const int*   in  = (const int*)d_in[0];
    const int*   tg  = (const int*)d_in[1];
    const float* w   = (const float*)d_in[2];
    float*       out = (float*)d_out;
    u32*         partial = (u32*)d_ws;  // fully overwritten every call

    dice_count<<<dim3(BLKS, NSAMP), 256, 0, stream>>>(in, tg, partial);
    dice_final<<<1, 192, 0, stream>>>(partial, w, out);
}